// Round 6
// baseline (8336.549 us; speedup 1.0000x reference)
//
#include <hip/hip_runtime.h>
#include <hip/hip_bf16.h>
#include <stdint.h>

typedef float f32x4 __attribute__((ext_vector_type(4)));
typedef short bf16x8 __attribute__((ext_vector_type(8)));

#define LDW 1024
#define BATCH_SH 20  // 1<<20 elements per 1024x1024 matrix

__device__ __forceinline__ float b2f(__hip_bfloat16 h) { return __bfloat162float(h); }
__device__ __forceinline__ __hip_bfloat16 f2b(float f) { return __float2bfloat16(f); }

// ---------------- Frobenius norm (2-stage) ----------------
__global__ void k_partial(const float* __restrict__ xin, float* __restrict__ partials) {
  const int b = blockIdx.y, ch = blockIdx.x, t = threadIdx.x;
  const size_t base = ((size_t)b << BATCH_SH) + (size_t)ch * 16384;
  float s = 0.f;
#pragma unroll
  for (int i = 0; i < 16; ++i) {
    f32x4 v = *reinterpret_cast<const f32x4*>(xin + base + (size_t)(i * 256 + t) * 4);
    s += v[0] * v[0] + v[1] * v[1] + v[2] * v[2] + v[3] * v[3];
  }
#pragma unroll
  for (int off = 32; off; off >>= 1) s += __shfl_down(s, off);
  __shared__ float red[4];
  if ((t & 63) == 0) red[t >> 6] = s;
  __syncthreads();
  if (t == 0) partials[b * 64 + ch] = red[0] + red[1] + red[2] + red[3];
}

__global__ void k_scale(const float* __restrict__ partials, float* __restrict__ scales) {
  const int b = blockIdx.x, t = threadIdx.x;
  float s = partials[b * 64 + t];
#pragma unroll
  for (int off = 32; off; off >>= 1) s += __shfl_down(s, off);
  if (t == 0) scales[b] = 1.1f / sqrtf(s);
}

// ---------------- scale + split + transpose-split ----------------
__global__ void k_scalesplit(const float* __restrict__ xin, const float* __restrict__ scales,
                             __hip_bfloat16* __restrict__ Xh, __hip_bfloat16* __restrict__ Xl,
                             __hip_bfloat16* __restrict__ XTh, __hip_bfloat16* __restrict__ XTl) {
  __shared__ float tile[64][65];
  const int b = blockIdx.z, tm = blockIdx.y, tn = blockIdx.x;
  const size_t boff = (size_t)b << BATCH_SH;
  const float s = scales[b];
  const int t = threadIdx.x, lr0 = t >> 6, lc = t & 63;
#pragma unroll
  for (int p = 0; p < 16; ++p) {
    const int lr = p * 4 + lr0;
    const size_t idx = boff + (size_t)(tm * 64 + lr) * LDW + tn * 64 + lc;
    const float v = xin[idx] * s;
    __hip_bfloat16 h = f2b(v);
    Xh[idx] = h;
    Xl[idx] = f2b(v - b2f(h));
    tile[lr][lc] = v;
  }
  __syncthreads();
#pragma unroll
  for (int p = 0; p < 16; ++p) {
    const int lr = p * 4 + lr0;
    const float v = tile[lc][lr];
    const size_t idx = boff + (size_t)(tn * 64 + lr) * LDW + tm * 64 + lc;
    __hip_bfloat16 h = f2b(v);
    XTh[idx] = h;
    XTl[idx] = f2b(v - b2f(h));
  }
}

// ---------------- split-bf16 GEMM: C = PA * PB^T, 256x256 tile, BK=64 ----------------
// Effective K = 3072 (3 bf16 segments). 512 threads = 8 waves (2M x 4N).
// 4-phase K-step schedule (m201-style port): each phase = {ds_read quadrant
// fragments + 2 ds_write (tile s+1 slice) + 2 global load (tile s+2 slice)
// -> s_barrier -> lgkmcnt(0)+sched_barrier -> setprio(1) 16 MFMA setprio(0)
// -> s_barrier}. vmcnt is never waited: stage loads issued one K-step early,
// compiler register deps resolve them. Reg-staged XOR chunk swizzle unchanged.
// MODE 1 (SYM):  C symmetric; 10 upper tiles; write splits at (i,j) and (j,i).
// MODE 2 (POLY): v = c2*C + c1*A + c0*I; symmetric writes like MODE 1.
// MODE 3 (XUP):  v = C; if(oh) splits + transposed splits; if(of) fp32.

#define SEGPTRS(S)                                                                        \
  const int seg_ = (S) >> 4, k0_ = ((S) & 15) << 6;                                       \
  const __hip_bfloat16* pa_ = seg_ == 0 ? pa0 : seg_ == 1 ? pa1 : pa2;                    \
  const __hip_bfloat16* pb_ = seg_ == 0 ? pb0 : seg_ == 1 ? pb1 : pb2;

#define LOAD_SLICE(S, P)                                                                  \
  {                                                                                       \
    SEGPTRS(S)                                                                            \
    const int r_ = (P) * 64 + srow;                                                       \
    sa[P] = *reinterpret_cast<const bf16x8*>(pa_ + boff + (size_t)(rowA + r_) * LDW +     \
                                             k0_ + chnk * 8);                             \
    sb[P] = *reinterpret_cast<const bf16x8*>(pb_ + boff + (size_t)(rowB + r_) * LDW +     \
                                             k0_ + chnk * 8);                             \
  }

#define DSW_SLICE(DB, P)                                                                  \
  {                                                                                       \
    char* wb_ = smem + (DB) * 65536;                                                      \
    const int r_ = (P) * 64 + srow;                                                       \
    const int sl_ = (chnk ^ (r_ & 7)) << 4;                                               \
    *reinterpret_cast<bf16x8*>(wb_ + r_ * 128 + sl_) = sa[P];                             \
    *reinterpret_cast<bf16x8*>(wb_ + 32768 + r_ * 128 + sl_) = sb[P];                     \
  }

#define DSREAD_AV(KK, MH)                                                                 \
  _Pragma("unroll") for (int i_ = 0; i_ < 4; ++i_)                                        \
      av[i_] = *reinterpret_cast<const bf16x8*>(smem + base + offA[KK][(MH) * 4 + i_]);

#define DSREAD_BV(KK)                                                                     \
  _Pragma("unroll") for (int i_ = 0; i_ < 4; ++i_)                                        \
      bv[i_] = *reinterpret_cast<const bf16x8*>(smem + base + offB[KK][i_]);

#define MFMA16(MH)                                                                        \
  __builtin_amdgcn_s_setprio(1);                                                          \
  _Pragma("unroll") for (int mi_ = 0; mi_ < 4; ++mi_)                                     \
      _Pragma("unroll") for (int ni_ = 0; ni_ < 4; ++ni_)                                 \
          acc[(MH) * 4 + mi_][ni_] = __builtin_amdgcn_mfma_f32_16x16x32_bf16(             \
              av[mi_], bv[ni_], acc[(MH) * 4 + mi_][ni_], 0, 0, 0);                       \
  __builtin_amdgcn_s_setprio(0);

#define BAR() __builtin_amdgcn_s_barrier()
#define LGKM0()                                       \
  asm volatile("s_waitcnt lgkmcnt(0)" ::: "memory"); \
  __builtin_amdgcn_sched_barrier(0)

// phase P = KK*2 + MH: reads (bv if MH==0) + av quadrant, stages slice P,
// barrier, drain, 16 MFMA, barrier.
#define PHASE(KK, MH, P)                                                                  \
  {                                                                                       \
    if ((MH) == 0) { DSREAD_BV(KK); }                                                     \
    DSREAD_AV(KK, MH);                                                                    \
    if (wr_ok) DSW_SLICE(wdb, P);                                                         \
    if (ld_ok) LOAD_SLICE(s + 2, P);                                                      \
    BAR();                                                                                \
    LGKM0();                                                                              \
    MFMA16(MH);                                                                           \
    BAR();                                                                                \
  }

template <int MODE>
__global__ __launch_bounds__(512, 2) void k_gemm(
    const __hip_bfloat16* __restrict__ pa0, const __hip_bfloat16* __restrict__ pa1,
    const __hip_bfloat16* __restrict__ pa2, const __hip_bfloat16* __restrict__ pb0,
    const __hip_bfloat16* __restrict__ pb1, const __hip_bfloat16* __restrict__ pb2,
    __hip_bfloat16* oh, __hip_bfloat16* ol,
    __hip_bfloat16* oth, __hip_bfloat16* otl,
    float* __restrict__ of,
    const __hip_bfloat16* __restrict__ eh, const __hip_bfloat16* __restrict__ el,
    const float* __restrict__ coef) {
  __shared__ __align__(16) char smem[131072];  // 2 bufs x (A 32KB + B 32KB)
  const int t = threadIdx.x;
  const int w = t >> 6, l = t & 63;
  const int wr = w >> 2, wc = w & 3;       // 2M x 4N wave grid
  const int srow = t >> 3, chnk = t & 7;   // staging map: 64 rows/slice, 8 chunks

  // Fully-bijective XCD-aware swizzle (m204): works for any gridDim.x.
  const int nwg = gridDim.x, q = nwg >> 3, r8 = nwg & 7;
  const int xcd = blockIdx.x & 7, o = blockIdx.x >> 3;
  const int wgid = (xcd < r8 ? xcd * (q + 1) : r8 * (q + 1) + (xcd - r8) * q) + o;

  int bat, tm, tn;
  if constexpr (MODE == 3) {
    bat = wgid >> 4;
    const int tile = wgid & 15;
    tm = tile >> 2; tn = tile & 3;
  } else {
    bat = (int)((unsigned)wgid / 10u);
    const int tile = wgid - bat * 10;
    tm = (tile < 4) ? 0 : (tile < 7) ? 1 : (tile < 9) ? 2 : 3;
    tn = (tile < 4) ? tile : (tile < 7) ? (tile - 3) : (tile < 9) ? (tile - 5) : 3;
  }
  const size_t boff = (size_t)bat << BATCH_SH;
  const int rowA = tm * 256, rowB = tn * 256;

  f32x4 acc[8][4];
#pragma unroll
  for (int i = 0; i < 8; ++i)
#pragma unroll
    for (int j = 0; j < 4; ++j) acc[i][j] = (f32x4){0.f, 0.f, 0.f, 0.f};

  // MFMA fragment LDS byte offsets (within a buffer), XOR chunk swizzle
  int offA[2][8], offB[2][4];
#pragma unroll
  for (int kk = 0; kk < 2; ++kk) {
    const int g = kk * 4 + (l >> 4);
#pragma unroll
    for (int mi = 0; mi < 8; ++mi) {
      const int rA = wr * 128 + mi * 16 + (l & 15);
      offA[kk][mi] = rA * 128 + ((g ^ (rA & 7)) << 4);
    }
#pragma unroll
    for (int ni = 0; ni < 4; ++ni) {
      const int rB = wc * 64 + ni * 16 + (l & 15);
      offB[kk][ni] = 32768 + rB * 128 + ((g ^ (rB & 7)) << 4);
    }
  }

  bf16x8 sa[4], sb[4];
  // prologue: stage tile 0 into buf0, prefetch tile 1 into regs
#pragma unroll
  for (int p = 0; p < 4; ++p) LOAD_SLICE(0, p);
#pragma unroll
  for (int p = 0; p < 4; ++p) DSW_SLICE(0, p);
#pragma unroll
  for (int p = 0; p < 4; ++p) LOAD_SLICE(1, p);
  LGKM0();
  BAR();

  for (int s = 0; s < 48; ++s) {
    const int base = (s & 1) * 65536;
    const int wdb = (s & 1) ^ 1;
    const bool wr_ok = (s + 1 < 48);
    const bool ld_ok = (s + 2 < 48);
    bf16x8 av[4], bv[4];
    PHASE(0, 0, 0)
    PHASE(0, 1, 1)
    PHASE(1, 0, 2)
    PHASE(1, 1, 3)
  }

  float c0 = 0.f, c1 = 0.f, c2 = 0.f;
  if constexpr (MODE == 2) { c0 = coef[0]; c1 = coef[1]; c2 = coef[2]; }
  const int r0 = tm * 256 + wr * 128 + ((l >> 4) << 2);
  const int cb = tn * 256 + wc * 64 + (l & 15);
#pragma unroll
  for (int mi = 0; mi < 8; ++mi) {
#pragma unroll
    for (int ni = 0; ni < 4; ++ni) {
      const int ccol = cb + ni * 16;
#pragma unroll
      for (int j = 0; j < 4; ++j) {
        const int rrow = r0 + mi * 16 + j;
        const size_t idx = boff + (size_t)rrow * LDW + ccol;
        const size_t tix = boff + (size_t)ccol * LDW + rrow;
        float v = acc[mi][ni][j];
        if constexpr (MODE == 2)
          v = c2 * v + c1 * (b2f(eh[idx]) + b2f(el[idx])) + (rrow == ccol ? c0 : 0.f);
        __hip_bfloat16 h = f2b(v);
        __hip_bfloat16 lo = f2b(v - b2f(h));
        if constexpr (MODE == 3) {
          if (oh) {
            oh[idx] = h; ol[idx] = lo;
            oth[tix] = h; otl[tix] = lo;
          }
          if (of) of[idx] = v;
        } else {
          oh[idx] = h; ol[idx] = lo;
          if (tm != tn) { oth[tix] = h; otl[tix] = lo; }
        }
      }
    }
  }
}

extern "C" void kernel_launch(void* const* d_in, const int* in_sizes, int n_in,
                              void* d_out, int out_size, void* d_ws, size_t ws_size,
                              hipStream_t stream) {
  (void)in_sizes; (void)n_in; (void)out_size;
  const float* xin = (const float*)d_in[0];
  const float* coef = (const float*)d_in[1];
  float* xout = (float*)d_out;

  // ws need: 8 bf16 buffers (4 pairs) x CH x 2MB = 16 MB/batch (+64KB slack)
  int CH = 64;
  while (CH > 1 && ((size_t)CH * 16u * 1024u * 1024u + 65536u) > ws_size) CH >>= 1;

  const size_t nE = (size_t)CH << BATCH_SH;
  __hip_bfloat16* P0h = (__hip_bfloat16*)d_ws;
  __hip_bfloat16* P0l = P0h + nE;
  __hip_bfloat16* P1h = P0l + nE;
  __hip_bfloat16* P1l = P1h + nE;
  __hip_bfloat16* P2h = P1l + nE;
  __hip_bfloat16* P2l = P2h + nE;
  __hip_bfloat16* XTh = P2l + nE;
  __hip_bfloat16* XTl = XTh + nE;
  float* partials = (float*)(XTl + nE);
  float* scales = partials + (size_t)CH * 64;

  for (int c = 0; c < 64; c += CH) {
    const float* xi = xin + ((size_t)c << BATCH_SH);
    float* X = xout + ((size_t)c << BATCH_SH);  // final fp32 output only
    k_partial<<<dim3(64, CH), 256, 0, stream>>>(xi, partials);
    k_scale<<<dim3(CH), 64, 0, stream>>>(partials, scales);
    k_scalesplit<<<dim3(16, 16, CH), 256, 0, stream>>>(xi, scales, P0h, P0l, XTh, XTl);

    // rotating pairs: X, A, B  (X_next reuses the dead A pair each iteration)
    __hip_bfloat16 *Xh = P0h, *Xl = P0l, *Ah = P1h, *Al = P1l, *Bh = P2h, *Bl = P2l;
    for (int it = 0; it < 5; ++it) {
      // A = XT * XT^T (symmetric, 10 upper tiles): hi*hi + hi*lo + lo*hi
      k_gemm<1><<<dim3(CH * 10), 512, 0, stream>>>(XTh, XTh, XTl, XTh, XTl, XTh,
                                                   Ah, Al, Ah, Al, nullptr,
                                                   nullptr, nullptr, nullptr);
      // B = c2*A^2 + c1*A + c0*I (symmetric, 10 upper tiles)
      k_gemm<2><<<dim3(CH * 10), 512, 0, stream>>>(Ah, Ah, Al, Ah, Al, Ah,
                                                   Bh, Bl, Bh, Bl, nullptr,
                                                   Ah, Al, coef);
      // X_next = X * B^T (B symmetric); splits -> dead A pair; XT splits in place
      k_gemm<3><<<dim3(CH * 16), 512, 0, stream>>>(Xh, Xh, Xl, Bh, Bl, Bh,
                                                   (it < 4) ? Ah : nullptr,
                                                   (it < 4) ? Al : nullptr,
                                                   XTh, XTl,
                                                   (it == 4) ? X : nullptr,
                                                   nullptr, nullptr, nullptr);
      // rotate (X, A, B) <- (A, B, X)
      __hip_bfloat16 *th = Xh, *tl = Xl;
      Xh = Ah; Xl = Al;
      Ah = Bh; Al = Bl;
      Bh = th; Bl = tl;
    }
  }
}

// Round 7
// 7894.643 us; speedup vs baseline: 1.0560x; 1.0560x over previous
//
#include <hip/hip_runtime.h>
#include <hip/hip_bf16.h>
#include <stdint.h>

typedef float f32x4 __attribute__((ext_vector_type(4)));
typedef short bf16x8 __attribute__((ext_vector_type(8)));

#define LDW 1024
#define BATCH_SH 20  // 1<<20 elements per 1024x1024 matrix

__device__ __forceinline__ float b2f(__hip_bfloat16 h) { return __bfloat162float(h); }
__device__ __forceinline__ __hip_bfloat16 f2b(float f) { return __float2bfloat16(f); }

__device__ __forceinline__ void gload16(const void* g, void* l) {
  __builtin_amdgcn_global_load_lds((const __attribute__((address_space(1))) void*)g,
                                   (__attribute__((address_space(3))) void*)l,
                                   16, 0, 0);
}

// ---------------- Frobenius norm (2-stage) ----------------
__global__ void k_partial(const float* __restrict__ xin, float* __restrict__ partials) {
  const int b = blockIdx.y, ch = blockIdx.x, t = threadIdx.x;
  const size_t base = ((size_t)b << BATCH_SH) + (size_t)ch * 16384;
  float s = 0.f;
#pragma unroll
  for (int i = 0; i < 16; ++i) {
    f32x4 v = *reinterpret_cast<const f32x4*>(xin + base + (size_t)(i * 256 + t) * 4);
    s += v[0] * v[0] + v[1] * v[1] + v[2] * v[2] + v[3] * v[3];
  }
#pragma unroll
  for (int off = 32; off; off >>= 1) s += __shfl_down(s, off);
  __shared__ float red[4];
  if ((t & 63) == 0) red[t >> 6] = s;
  __syncthreads();
  if (t == 0) partials[b * 64 + ch] = red[0] + red[1] + red[2] + red[3];
}

__global__ void k_scale(const float* __restrict__ partials, float* __restrict__ scales) {
  const int b = blockIdx.x, t = threadIdx.x;
  float s = partials[b * 64 + t];
#pragma unroll
  for (int off = 32; off; off >>= 1) s += __shfl_down(s, off);
  if (t == 0) scales[b] = 1.1f / sqrtf(s);
}

// ---------------- scale + split + transpose-split ----------------
__global__ void k_scalesplit(const float* __restrict__ xin, const float* __restrict__ scales,
                             __hip_bfloat16* __restrict__ Xh, __hip_bfloat16* __restrict__ Xl,
                             __hip_bfloat16* __restrict__ XTh, __hip_bfloat16* __restrict__ XTl) {
  __shared__ float tile[64][65];
  const int b = blockIdx.z, tm = blockIdx.y, tn = blockIdx.x;
  const size_t boff = (size_t)b << BATCH_SH;
  const float s = scales[b];
  const int t = threadIdx.x, lr0 = t >> 6, lc = t & 63;
#pragma unroll
  for (int p = 0; p < 16; ++p) {
    const int lr = p * 4 + lr0;
    const size_t idx = boff + (size_t)(tm * 64 + lr) * LDW + tn * 64 + lc;
    const float v = xin[idx] * s;
    __hip_bfloat16 h = f2b(v);
    Xh[idx] = h;
    Xl[idx] = f2b(v - b2f(h));
    tile[lr][lc] = v;
  }
  __syncthreads();
#pragma unroll
  for (int p = 0; p < 16; ++p) {
    const int lr = p * 4 + lr0;
    const float v = tile[lc][lr];
    const size_t idx = boff + (size_t)(tn * 64 + lr) * LDW + tm * 64 + lc;
    __hip_bfloat16 h = f2b(v);
    XTh[idx] = h;
    XTl[idx] = f2b(v - b2f(h));
  }
}

// ---------------- split-bf16 GEMM: C = PA * PB^T, 256x256 tile, BK=64 ----------------
// Effective K = 3072 (3 bf16 segments). 512 threads = 8 waves (2M x 4N).
// Round-5 schedule (1 raw barrier per K-step), but staging via global_load_lds:
// linear LDS dest (wave-uniform base + lane*16) + XOR-pre-swizzled GLOBAL source
// (rule #21) — image identical to round-5's reg-staged DSWRITE, so read offsets
// are unchanged. vmcnt(0)+lgkmcnt(0) drained once per step before the barrier;
// tile s+1's loads are issued at step-s top, so the drain is cheap.
// MODE 1 (SYM):  C symmetric; 10 upper tiles; write splits at (i,j) and (j,i).
// MODE 2 (POLY): v = c2*C + c1*A + c0*I; symmetric writes like MODE 1.
// MODE 3 (XUP):  v = C; if(oh) splits + transposed splits; if(of) fp32.

#define SEGPTRS(S)                                                                        \
  const int seg_ = (S) >> 4, k0_ = ((S) & 15) << 6;                                       \
  const __hip_bfloat16* pa_ = seg_ == 0 ? pa0 : seg_ == 1 ? pa1 : pa2;                    \
  const __hip_bfloat16* pb_ = seg_ == 0 ? pb0 : seg_ == 1 ? pb1 : pb2;

// lane l of wave w stages row r = it*64 + w*8 + (l>>3), global chunk ((l&7)^(l>>3)),
// into linear LDS slot (row base + l*16). Image: LDS[r][slot] = chunk slot^(r&7),
// identical to the round-5 reg-staged image (r&7 == l>>3 here).
#define STAGE_GL(DB, S)                                                                   \
  {                                                                                       \
    SEGPTRS(S)                                                                            \
    char* lb_ = smem + (DB) * 65536;                                                      \
    _Pragma("unroll") for (int it_ = 0; it_ < 4; ++it_) {                                 \
      const int r_ = it_ * 64 + w * 8 + (l >> 3);                                         \
      const int kx_ = k0_ + (((l & 7) ^ (l >> 3)) << 3);                                  \
      gload16(pa_ + boff + (size_t)(rowA + r_) * LDW + kx_,                               \
              lb_ + (it_ * 64 + w * 8) * 128 + l * 16);                                   \
      gload16(pb_ + boff + (size_t)(rowB + r_) * LDW + kx_,                               \
              lb_ + 32768 + (it_ * 64 + w * 8) * 128 + l * 16);                           \
    }                                                                                     \
  }

#define MFMA_PHASE(KK, BASE)                                                              \
  {                                                                                       \
    bf16x8 av[8], bv[4];                                                                  \
    _Pragma("unroll") for (int mi_ = 0; mi_ < 8; ++mi_)                                   \
        av[mi_] = *reinterpret_cast<const bf16x8*>(smem + (BASE) + offA[KK][mi_]);        \
    _Pragma("unroll") for (int ni_ = 0; ni_ < 4; ++ni_)                                   \
        bv[ni_] = *reinterpret_cast<const bf16x8*>(smem + (BASE) + offB[KK][ni_]);        \
    __builtin_amdgcn_s_setprio(1);                                                        \
    _Pragma("unroll") for (int mi_ = 0; mi_ < 8; ++mi_)                                   \
        _Pragma("unroll") for (int ni_ = 0; ni_ < 4; ++ni_)                               \
            acc[mi_][ni_] = __builtin_amdgcn_mfma_f32_16x16x32_bf16(                      \
                av[mi_], bv[ni_], acc[mi_][ni_], 0, 0, 0);                                \
    __builtin_amdgcn_s_setprio(0);                                                        \
  }

template <int MODE>
__global__ __launch_bounds__(512, 2) void k_gemm(
    const __hip_bfloat16* __restrict__ pa0, const __hip_bfloat16* __restrict__ pa1,
    const __hip_bfloat16* __restrict__ pa2, const __hip_bfloat16* __restrict__ pb0,
    const __hip_bfloat16* __restrict__ pb1, const __hip_bfloat16* __restrict__ pb2,
    __hip_bfloat16* oh, __hip_bfloat16* ol,
    __hip_bfloat16* oth, __hip_bfloat16* otl,
    float* __restrict__ of,
    const __hip_bfloat16* __restrict__ eh, const __hip_bfloat16* __restrict__ el,
    const float* __restrict__ coef) {
  __shared__ __align__(16) char smem[131072];  // 2 bufs x (A 32KB + B 32KB)
  const int t = threadIdx.x;
  const int w = t >> 6, l = t & 63;
  const int wr = w >> 2, wc = w & 3;  // 2M x 4N wave grid

  // Fully-bijective XCD-aware swizzle (m204): works for any gridDim.x.
  const int nwg = gridDim.x, q = nwg >> 3, r8 = nwg & 7;
  const int xcd = blockIdx.x & 7, o = blockIdx.x >> 3;
  const int wgid = (xcd < r8 ? xcd * (q + 1) : r8 * (q + 1) + (xcd - r8) * q) + o;

  int bat, tm, tn;
  if constexpr (MODE == 3) {
    bat = wgid >> 4;
    const int tile = wgid & 15;
    tm = tile >> 2; tn = tile & 3;
  } else {
    bat = (int)((unsigned)wgid / 10u);
    const int tile = wgid - bat * 10;
    tm = (tile < 4) ? 0 : (tile < 7) ? 1 : (tile < 9) ? 2 : 3;
    tn = (tile < 4) ? tile : (tile < 7) ? (tile - 3) : (tile < 9) ? (tile - 5) : 3;
  }
  const size_t boff = (size_t)bat << BATCH_SH;
  const int rowA = tm * 256, rowB = tn * 256;

  f32x4 acc[8][4];
#pragma unroll
  for (int i = 0; i < 8; ++i)
#pragma unroll
    for (int j = 0; j < 4; ++j) acc[i][j] = (f32x4){0.f, 0.f, 0.f, 0.f};

  // MFMA fragment LDS byte offsets (within a buffer), XOR chunk swizzle
  int offA[2][8], offB[2][4];
#pragma unroll
  for (int kk = 0; kk < 2; ++kk) {
    const int g = kk * 4 + (l >> 4);
#pragma unroll
    for (int mi = 0; mi < 8; ++mi) {
      const int rA = wr * 128 + mi * 16 + (l & 15);
      offA[kk][mi] = rA * 128 + ((g ^ (rA & 7)) << 4);
    }
#pragma unroll
    for (int ni = 0; ni < 4; ++ni) {
      const int rB = wc * 64 + ni * 16 + (l & 15);
      offB[kk][ni] = 32768 + rB * 128 + ((g ^ (rB & 7)) << 4);
    }
  }

  // prologue: stage tile 0 into buf0, drain, converge
  STAGE_GL(0, 0);
  asm volatile("s_waitcnt vmcnt(0)" ::: "memory");
  __builtin_amdgcn_sched_barrier(0);
  __builtin_amdgcn_s_barrier();
  __builtin_amdgcn_sched_barrier(0);

  for (int s = 0; s < 48; ++s) {
    const int base = (s & 1) * 65536;
    if (s + 1 < 48) STAGE_GL((s & 1) ^ 1, s + 1);  // issue early; in flight under MFMA
    __builtin_amdgcn_sched_barrier(0);             // pin issue before compute
    MFMA_PHASE(0, base);
    MFMA_PHASE(1, base);
    // tile s+1 loads retired (issued ~full step ago -> cheap) + my reads done (WAR)
    asm volatile("s_waitcnt vmcnt(0) lgkmcnt(0)" ::: "memory");
    __builtin_amdgcn_sched_barrier(0);
    __builtin_amdgcn_s_barrier();
    __builtin_amdgcn_sched_barrier(0);
  }

  float c0 = 0.f, c1 = 0.f, c2 = 0.f;
  if constexpr (MODE == 2) { c0 = coef[0]; c1 = coef[1]; c2 = coef[2]; }
  const int r0 = tm * 256 + wr * 128 + ((l >> 4) << 2);
  const int cb = tn * 256 + wc * 64 + (l & 15);
#pragma unroll
  for (int mi = 0; mi < 8; ++mi) {
#pragma unroll
    for (int ni = 0; ni < 4; ++ni) {
      const int ccol = cb + ni * 16;
#pragma unroll
      for (int j = 0; j < 4; ++j) {
        const int rrow = r0 + mi * 16 + j;
        const size_t idx = boff + (size_t)rrow * LDW + ccol;
        const size_t tix = boff + (size_t)ccol * LDW + rrow;
        float v = acc[mi][ni][j];
        if constexpr (MODE == 2)
          v = c2 * v + c1 * (b2f(eh[idx]) + b2f(el[idx])) + (rrow == ccol ? c0 : 0.f);
        __hip_bfloat16 h = f2b(v);
        __hip_bfloat16 lo = f2b(v - b2f(h));
        if constexpr (MODE == 3) {
          if (oh) {
            oh[idx] = h; ol[idx] = lo;
            oth[tix] = h; otl[tix] = lo;
          }
          if (of) of[idx] = v;
        } else {
          oh[idx] = h; ol[idx] = lo;
          if (tm != tn) { oth[tix] = h; otl[tix] = lo; }
        }
      }
    }
  }
}

extern "C" void kernel_launch(void* const* d_in, const int* in_sizes, int n_in,
                              void* d_out, int out_size, void* d_ws, size_t ws_size,
                              hipStream_t stream) {
  (void)in_sizes; (void)n_in; (void)out_size;
  const float* xin = (const float*)d_in[0];
  const float* coef = (const float*)d_in[1];
  float* xout = (float*)d_out;

  // ws need: 8 bf16 buffers (4 pairs) x CH x 2MB = 16 MB/batch (+64KB slack)
  int CH = 64;
  while (CH > 1 && ((size_t)CH * 16u * 1024u * 1024u + 65536u) > ws_size) CH >>= 1;

  const size_t nE = (size_t)CH << BATCH_SH;
  __hip_bfloat16* P0h = (__hip_bfloat16*)d_ws;
  __hip_bfloat16* P0l = P0h + nE;
  __hip_bfloat16* P1h = P0l + nE;
  __hip_bfloat16* P1l = P1h + nE;
  __hip_bfloat16* P2h = P1l + nE;
  __hip_bfloat16* P2l = P2h + nE;
  __hip_bfloat16* XTh = P2l + nE;
  __hip_bfloat16* XTl = XTh + nE;
  float* partials = (float*)(XTl + nE);
  float* scales = partials + (size_t)CH * 64;

  for (int c = 0; c < 64; c += CH) {
    const float* xi = xin + ((size_t)c << BATCH_SH);
    float* X = xout + ((size_t)c << BATCH_SH);  // final fp32 output only
    k_partial<<<dim3(64, CH), 256, 0, stream>>>(xi, partials);
    k_scale<<<dim3(CH), 64, 0, stream>>>(partials, scales);
    k_scalesplit<<<dim3(16, 16, CH), 256, 0, stream>>>(xi, scales, P0h, P0l, XTh, XTl);

    // rotating pairs: X, A, B  (X_next reuses the dead A pair each iteration)
    __hip_bfloat16 *Xh = P0h, *Xl = P0l, *Ah = P1h, *Al = P1l, *Bh = P2h, *Bl = P2l;
    for (int it = 0; it < 5; ++it) {
      // A = XT * XT^T (symmetric, 10 upper tiles): hi*hi + hi*lo + lo*hi
      k_gemm<1><<<dim3(CH * 10), 512, 0, stream>>>(XTh, XTh, XTl, XTh, XTl, XTh,
                                                   Ah, Al, Ah, Al, nullptr,
                                                   nullptr, nullptr, nullptr);
      // B = c2*A^2 + c1*A + c0*I (symmetric, 10 upper tiles)
      k_gemm<2><<<dim3(CH * 10), 512, 0, stream>>>(Ah, Ah, Al, Ah, Al, Ah,
                                                   Bh, Bl, Bh, Bl, nullptr,
                                                   Ah, Al, coef);
      // X_next = X * B^T (B symmetric); splits -> dead A pair; XT splits in place
      k_gemm<3><<<dim3(CH * 16), 512, 0, stream>>>(Xh, Xh, Xl, Bh, Bl, Bh,
                                                   (it < 4) ? Ah : nullptr,
                                                   (it < 4) ? Al : nullptr,
                                                   XTh, XTl,
                                                   (it == 4) ? X : nullptr,
                                                   nullptr, nullptr, nullptr);
      // rotate (X, A, B) <- (A, B, X)
      __hip_bfloat16 *th = Xh, *tl = Xl;
      Xh = Ah; Xl = Al;
      Ah = Bh; Al = Bl;
      Bh = th; Bl = tl;
    }
  }
}